// Round 2
// baseline (1771.894 us; speedup 1.0000x reference)
//
#include <hip/hip_runtime.h>
#include <math.h>

// Problem constants (fixed by reference setup_inputs)
#define NN  50000
#define EE  400000
#define DD  64
#define HH  4
#define HC  256      // H * C
#define EDD 16

// wave64 butterfly sum — all lanes end with the total
__device__ __forceinline__ float wsum(float v) {
#pragma unroll
    for (int m = 32; m > 0; m >>= 1) v += __shfl_xor(v, m, 64);
    return v;
}

// order-preserving float<->uint map for atomicMax on signed floats
__device__ __forceinline__ unsigned fmapu(float f) {
    unsigned u = __float_as_uint(f);
    return (u & 0x80000000u) ? ~u : (u | 0x80000000u);
}
__device__ __forceinline__ float funmapu(unsigned u) {
    u = (u & 0x80000000u) ? (u & 0x7FFFFFFFu) : ~u;
    return __uint_as_float(u);
}
// fmapu(-inf) -> 0x007FFFFF : init value for amax
#define AMAX_INIT 0x007FFFFFu

__device__ __forceinline__ float gelu_exact(float x) {
    return 0.5f * x * (1.0f + erff(x * 0.70710678118654752440f));
}

// ---------- init fills (ws is poisoned 0xAA every call) ----------
__global__ void fill_f32(float* __restrict__ p, float v, int n) {
    int i = blockIdx.x * blockDim.x + threadIdx.x;
    int s = gridDim.x * blockDim.x;
    for (; i < n; i += s) p[i] = v;
}
__global__ void fill_u32(unsigned* __restrict__ p, unsigned v, int n) {
    int i = blockIdx.x * blockDim.x + threadIdx.x;
    int s = gridDim.x * blockDim.x;
    for (; i < n; i += s) p[i] = v;
}

// ---------- node GEMM: Y[N,256] = X[N,64] @ W[64,256] + b ----------
// block = 256 threads, 32 rows per block, thread col = tid
// X tile staged transposed in LDS (broadcast reads); W streamed from L1/L2.
__global__ __launch_bounds__(256) void gemm_node(
    const float* __restrict__ X, const float* __restrict__ W,
    const float* __restrict__ b, float* __restrict__ Y, int nrows)
{
    __shared__ float xs[64][33];   // [k][r], +1 pad breaks write conflicts
    const int tid = threadIdx.x;
    const int base = blockIdx.x * 32;

    // coalesced read, transposed write
    for (int i = tid; i < 32 * 64; i += 256) {
        int r = i >> 6, k = i & 63;
        int row = base + r;
        xs[k][r] = (row < nrows) ? X[(long)row * 64 + k] : 0.f;
    }
    __syncthreads();

    float acc[32];
#pragma unroll
    for (int r = 0; r < 32; r++) acc[r] = 0.f;
    const int col = tid;
#pragma unroll 4
    for (int k = 0; k < 64; k++) {
        float wk = W[k * 256 + col];      // wave-coalesced, L1/L2 resident
#pragma unroll
        for (int r = 0; r < 32; r++) acc[r] += xs[k][r] * wk;
    }
    float bb = b[col];
    for (int r = 0; r < 32; r++) {
        int row = base + r;
        if (row < nrows) Y[(long)row * 256 + col] = acc[r] + bb;
    }
}

// ---------- edge pass A: alpha[e,h] + segment max over dst ----------
// one wave per edge; lane = channel c
__global__ __launch_bounds__(256) void edge_alpha_k(
    const float* __restrict__ xl, const float* __restrict__ xr,
    const int* __restrict__ ei, const float* __restrict__ ea,
    const float* __restrict__ We, const float* __restrict__ att,
    float* __restrict__ alpha, unsigned* __restrict__ amax)
{
    __shared__ float we_s[EDD * HC];   // 16 KB
    __shared__ float att_s[HC];
    for (int i = threadIdx.x; i < EDD * HC; i += 256) we_s[i] = We[i];
    if (threadIdx.x < HC) att_s[threadIdx.x] = att[threadIdx.x];
    __syncthreads();

    const int lane = threadIdx.x & 63;
    const int e = blockIdx.x * 4 + (threadIdx.x >> 6);
    if (e >= EE) return;
    const int src = ei[e];
    const int dst = ei[EE + e];

    // broadcast this edge's 16 attrs to all lanes
    float ev = (lane < EDD) ? ea[(long)e * EDD + lane] : 0.f;
    float eak[EDD];
#pragma unroll
    for (int k = 0; k < EDD; k++) eak[k] = __shfl(ev, k, 64);

    const float* xls = xl + (long)src * HC;
    const float* xrd = xr + (long)dst * HC;

#pragma unroll
    for (int h = 0; h < HH; h++) {
        const int hc = h * 64 + lane;
        float ez = 0.f;
#pragma unroll
        for (int k = 0; k < EDD; k++) ez += eak[k] * we_s[k * HC + hc];
        float s = xls[hc] + xrd[hc] + ez;
        s = (s > 0.f) ? s : 0.2f * s;           // leaky_relu 0.2
        float p = wsum(s * att_s[hc]);
        if (lane == h) {
            alpha[(long)e * HH + h] = p;
            atomicMax(&amax[(long)dst * HH + h], fmapu(p));
        }
    }
}

// ---------- edge pass B: ex, denom, and numerator aggregation ----------
// out_agg[dst] += ex * xl[src]; denom[dst] += ex   (divide at node stage)
__global__ __launch_bounds__(256) void edge_agg_k(
    const int* __restrict__ ei, const float* __restrict__ alpha,
    const unsigned* __restrict__ amax, const float* __restrict__ xl,
    float* __restrict__ denom, float* __restrict__ oa)
{
    const int lane = threadIdx.x & 63;
    const int e = blockIdx.x * 4 + (threadIdx.x >> 6);
    if (e >= EE) return;
    const int src = ei[e];
    const int dst = ei[EE + e];

    float ex = 0.f;
    if (lane < HH) {
        float am = funmapu(amax[(long)dst * HH + lane]);
        if (!isfinite(am)) am = 0.f;            // matches ref where(isfinite)
        ex = expf(alpha[(long)e * HH + lane] - am);
        atomicAdd(&denom[(long)dst * HH + lane], ex);
    }
    const float e0 = __shfl(ex, 0, 64);
    const float e1 = __shfl(ex, 1, 64);
    const float e2 = __shfl(ex, 2, 64);
    const float e3 = __shfl(ex, 3, 64);

    const float* xls = xl + (long)src * HC;
    float* oad = oa + (long)dst * HC;
    atomicAdd(&oad[lane],        e0 * xls[lane]);
    atomicAdd(&oad[64 + lane],   e1 * xls[64 + lane]);
    atomicAdd(&oad[128 + lane],  e2 * xls[128 + lane]);
    atomicAdd(&oad[192 + lane],  e3 * xls[192 + lane]);
}

// ---------- node epilogue: head mean + bias + LN (+ GELU / residual) ----------
// mode 0: x1 = gelu(LN(v))              -> f32 scratch
// mode 1: out = gelu(LN(v) + identity)  -> f32 out
__global__ __launch_bounds__(256) void node_post_k(
    const float* __restrict__ oa, const float* __restrict__ denom,
    const float* __restrict__ bias, const float* __restrict__ lng,
    const float* __restrict__ lnb, const float* __restrict__ identity,
    float* __restrict__ x1out, float* __restrict__ fout, int mode)
{
    const int lane = threadIdx.x & 63;
    const int n = blockIdx.x * 4 + (threadIdx.x >> 6);
    if (n >= NN) return;

    float v = 0.f;
#pragma unroll
    for (int h = 0; h < HH; h++)
        v += oa[(long)n * HC + h * 64 + lane] / (denom[(long)n * HH + h] + 1e-16f);
    v = v * 0.25f + bias[lane];

    float mu  = wsum(v) * (1.0f / 64.0f);
    float d   = v - mu;
    float var = wsum(d * d) * (1.0f / 64.0f);
    float y   = d * rsqrtf(var + 1e-5f) * lng[lane] + lnb[lane];

    if (mode == 0) {
        x1out[(long)n * DD + lane] = gelu_exact(y);
    } else {
        float o = gelu_exact(y + identity[(long)n * DD + lane]);
        fout[(long)n * DD + lane] = o;
    }
}

// ---------- launch ----------
extern "C" void kernel_launch(void* const* d_in, const int* in_sizes, int n_in,
                              void* d_out, int out_size, void* d_ws, size_t ws_size,
                              hipStream_t stream) {
    (void)in_sizes; (void)n_in; (void)out_size; (void)ws_size;

    const float* h     = (const float*)d_in[0];
    const int*   ei    = (const int*)d_in[1];
    const float* ea    = (const float*)d_in[2];
    const float* g1Wl  = (const float*)d_in[3];
    const float* g1bl  = (const float*)d_in[4];
    const float* g1Wr  = (const float*)d_in[5];
    const float* g1br  = (const float*)d_in[6];
    const float* g1We  = (const float*)d_in[7];
    const float* g1att = (const float*)d_in[8];
    const float* g1bias= (const float*)d_in[9];
    const float* ln1g  = (const float*)d_in[10];
    const float* ln1b  = (const float*)d_in[11];
    const float* g2Wl  = (const float*)d_in[12];
    const float* g2bl  = (const float*)d_in[13];
    const float* g2Wr  = (const float*)d_in[14];
    const float* g2br  = (const float*)d_in[15];
    const float* g2We  = (const float*)d_in[16];
    const float* g2att = (const float*)d_in[17];
    const float* g2bias= (const float*)d_in[18];
    const float* ln2g  = (const float*)d_in[19];
    const float* ln2b  = (const float*)d_in[20];

    float* out = (float*)d_out;

    // workspace layout (floats): total 43.6M f32 = 174.4 MB
    float*    ws    = (float*)d_ws;
    float*    xl    = ws;                    // 12.8M
    float*    xr    = ws + 12800000;         // 12.8M
    float*    oa    = ws + 25600000;         // 12.8M  (denom directly after -> one zero-fill)
    float*    denom = ws + 38400000;         // 0.2M
    float*    alpha = ws + 38600000;         // 1.6M
    unsigned* amax  = (unsigned*)(ws + 40200000); // 0.2M
    float*    x1    = ws + 40400000;         // 3.2M

    const int GEMM_BLOCKS = (NN + 31) / 32;  // 1563
    const int EDGE_BLOCKS = (EE + 3) / 4;    // 100000
    const int NODE_BLOCKS = (NN + 3) / 4;    // 12500

    // ----- layer 1 -----
    gemm_node<<<GEMM_BLOCKS, 256, 0, stream>>>(h, g1Wl, g1bl, xl, NN);
    gemm_node<<<GEMM_BLOCKS, 256, 0, stream>>>(h, g1Wr, g1br, xr, NN);
    fill_f32<<<2048, 256, 0, stream>>>(oa, 0.f, NN * HC + NN * HH);   // oa + denom
    fill_u32<<<512, 256, 0, stream>>>(amax, AMAX_INIT, NN * HH);
    edge_alpha_k<<<EDGE_BLOCKS, 256, 0, stream>>>(xl, xr, ei, ea, g1We, g1att, alpha, amax);
    edge_agg_k<<<EDGE_BLOCKS, 256, 0, stream>>>(ei, alpha, amax, xl, denom, oa);
    node_post_k<<<NODE_BLOCKS, 256, 0, stream>>>(oa, denom, g1bias, ln1g, ln1b, h, x1, out, 0);

    // ----- layer 2 -----
    gemm_node<<<GEMM_BLOCKS, 256, 0, stream>>>(x1, g2Wl, g2bl, xl, NN);
    gemm_node<<<GEMM_BLOCKS, 256, 0, stream>>>(x1, g2Wr, g2br, xr, NN);
    fill_f32<<<2048, 256, 0, stream>>>(oa, 0.f, NN * HC + NN * HH);
    fill_u32<<<512, 256, 0, stream>>>(amax, AMAX_INIT, NN * HH);
    edge_alpha_k<<<EDGE_BLOCKS, 256, 0, stream>>>(xl, xr, ei, ea, g2We, g2att, alpha, amax);
    edge_agg_k<<<EDGE_BLOCKS, 256, 0, stream>>>(ei, alpha, amax, xl, denom, oa);
    node_post_k<<<NODE_BLOCKS, 256, 0, stream>>>(oa, denom, g2bias, ln2g, ln2b, h, x1, out, 1);
}

// Round 3
// 1111.806 us; speedup vs baseline: 1.5937x; 1.5937x over previous
//
#include <hip/hip_runtime.h>
#include <math.h>

// Problem constants (fixed by reference setup_inputs)
#define NN  50000
#define EE  400000
#define DD  64
#define HH  4
#define HC  256      // H * C
#define EDD 16

#define GAT_BLOCKS 3200   // 12800 waves, ~4 nodes/wave

// wave64 butterfly sum — all lanes end with the total
__device__ __forceinline__ float wsum(float v) {
#pragma unroll
    for (int m = 32; m > 0; m >>= 1) v += __shfl_xor(v, m, 64);
    return v;
}

__device__ __forceinline__ float gelu_exact(float x) {
    return 0.5f * x * (1.0f + erff(x * 0.70710678118654752440f));
}

// ---------- fills ----------
__global__ void fill_u32(unsigned* __restrict__ p, unsigned v, int n) {
    int i = blockIdx.x * blockDim.x + threadIdx.x;
    int s = gridDim.x * blockDim.x;
    for (; i < n; i += s) p[i] = v;
}

// ---------- CSR build (counting sort by dst; once per call, shared by both layers) ----------
__global__ void hist_k(const int* __restrict__ ei, int* __restrict__ deg) {
    int e = blockIdx.x * 256 + threadIdx.x;
    if (e < EE) atomicAdd(&deg[ei[EE + e]], 1);
}

// per-256-block exclusive scan + block sums
__global__ void scan1_k(const int* __restrict__ deg, int* __restrict__ rowptr,
                        int* __restrict__ bsum) {
    __shared__ int s[256];
    int t = threadIdx.x, i = blockIdx.x * 256 + t;
    int v = (i < NN) ? deg[i] : 0;
    s[t] = v; __syncthreads();
    for (int o = 1; o < 256; o <<= 1) {
        int u = (t >= o) ? s[t - o] : 0;
        __syncthreads();
        s[t] += u;
        __syncthreads();
    }
    if (i < NN) rowptr[i] = s[t] - v;       // block-local exclusive
    if (t == 255) bsum[blockIdx.x] = s[255];
}
__global__ void scan2_k(int* __restrict__ bsum, int nb) {
    __shared__ int s[256];
    int t = threadIdx.x;
    int v = (t < nb) ? bsum[t] : 0;
    s[t] = v; __syncthreads();
    for (int o = 1; o < 256; o <<= 1) {
        int u = (t >= o) ? s[t - o] : 0;
        __syncthreads();
        s[t] += u;
        __syncthreads();
    }
    if (t < nb) bsum[t] = s[t] - v;         // exclusive over blocks
}
__global__ void scan3_k(int* __restrict__ rowptr, const int* __restrict__ bsum,
                        int* __restrict__ cursor) {
    int i = blockIdx.x * 256 + threadIdx.x;
    if (i < NN) {
        int r = rowptr[i] + bsum[blockIdx.x];
        rowptr[i] = r;
        cursor[i] = r;
    }
    if (i == 0) rowptr[NN] = EE;
}
__global__ void scatter_k(const int* __restrict__ ei, int* __restrict__ cursor,
                          int* __restrict__ srcs, int* __restrict__ eidx) {
    int e = blockIdx.x * 256 + threadIdx.x;
    if (e >= EE) return;
    int dst = ei[EE + e];
    int pos = atomicAdd(&cursor[dst], 1);
    srcs[pos] = ei[e];
    eidx[pos] = e;
}

// ---------- node GEMM: Y[N,256] = X[N,64] @ W[64,256] + b ----------
__global__ __launch_bounds__(256) void gemm_node(
    const float* __restrict__ X, const float* __restrict__ W,
    const float* __restrict__ b, float* __restrict__ Y, int nrows)
{
    __shared__ float xs[64][33];
    const int tid = threadIdx.x;
    const int base = blockIdx.x * 32;

    for (int i = tid; i < 32 * 64; i += 256) {
        int r = i >> 6, k = i & 63;
        int row = base + r;
        xs[k][r] = (row < nrows) ? X[(long)row * 64 + k] : 0.f;
    }
    __syncthreads();

    float acc[32];
#pragma unroll
    for (int r = 0; r < 32; r++) acc[r] = 0.f;
    const int col = tid;
#pragma unroll 4
    for (int k = 0; k < 64; k++) {
        float wk = W[k * 256 + col];
#pragma unroll
        for (int r = 0; r < 32; r++) acc[r] += xs[k][r] * wk;
    }
    float bb = b[col];
    for (int r = 0; r < 32; r++) {
        int row = base + r;
        if (row < nrows) Y[(long)row * 256 + col] = acc[r] + bb;
    }
}

// ---------- fused GAT aggregation: one wave per dst node ----------
// online softmax per head (m,l rescale), aggregation in registers,
// fused head-mean + bias + LN + GELU (+residual) epilogue. No LDS.
__global__ __launch_bounds__(256) void gat_fused_k(
    const int* __restrict__ rowptr, const int* __restrict__ srcs,
    const int* __restrict__ eidx, const float* __restrict__ ea,
    const float* __restrict__ We, const float* __restrict__ att,
    const float* __restrict__ xl, const float* __restrict__ xr,
    const float* __restrict__ bias, const float* __restrict__ lng,
    const float* __restrict__ lnb, const float* __restrict__ identity,
    float* __restrict__ x1out, float* __restrict__ outp, int mode)
{
    const int lane = threadIdx.x & 63;
    const int wid  = blockIdx.x * 4 + (threadIdx.x >> 6);

    // this lane's We column across k, per head; att per head — in registers
    float wreg[HH][EDD];
#pragma unroll
    for (int h = 0; h < HH; h++)
#pragma unroll
        for (int k = 0; k < EDD; k++) wreg[h][k] = We[k * HC + h * 64 + lane];
    float attr[HH];
#pragma unroll
    for (int h = 0; h < HH; h++) attr[h] = att[h * 64 + lane];
    const float bia = bias[lane];
    const float lg  = lng[lane];
    const float lb  = lnb[lane];

    for (int n = wid; n < NN; n += GAT_BLOCKS * 4) {
        const int p0 = rowptr[n], p1 = rowptr[n + 1];
        float xrv[HH];
#pragma unroll
        for (int h = 0; h < HH; h++) xrv[h] = xr[(long)n * HC + h * 64 + lane];

        float m[HH], l[HH], acc[HH];
#pragma unroll
        for (int h = 0; h < HH; h++) { m[h] = -INFINITY; l[h] = 0.f; acc[h] = 0.f; }

        for (int p = p0; p < p1; p++) {
            const int src = __builtin_amdgcn_readfirstlane(srcs[p]);
            const int e   = __builtin_amdgcn_readfirstlane(eidx[p]);
            float ev = (lane < EDD) ? ea[(long)e * EDD + lane] : 0.f;
            float eak[EDD];
#pragma unroll
            for (int k = 0; k < EDD; k++) eak[k] = __shfl(ev, k, 64);

#pragma unroll
            for (int h = 0; h < HH; h++) {
                const float xlv = xl[(long)src * HC + h * 64 + lane];
                float ez = 0.f;
#pragma unroll
                for (int k = 0; k < EDD; k++) ez += eak[k] * wreg[h][k];
                float s = xlv + xrv[h] + ez;
                s = (s > 0.f) ? s : 0.2f * s;            // leaky_relu 0.2
                const float pl = wsum(s * attr[h]);       // attention logit
                const float mn = fmaxf(m[h], pl);
                const float c  = expf(m[h] - mn);         // 0 on first edge
                const float w  = expf(pl - mn);
                l[h]   = l[h] * c + w;
                acc[h] = acc[h] * c + w * xlv;
                m[h]   = mn;
            }
        }

        // epilogue: head mean + bias + LN + GELU (+ residual)
        float v = 0.f;
#pragma unroll
        for (int h = 0; h < HH; h++) v += acc[h] / (l[h] + 1e-16f);
        v = v * 0.25f + bia;

        const float mu  = wsum(v) * (1.0f / 64.0f);
        const float d   = v - mu;
        const float var = wsum(d * d) * (1.0f / 64.0f);
        const float y   = d * rsqrtf(var + 1e-5f) * lg + lb;

        if (mode == 0) {
            x1out[(long)n * DD + lane] = gelu_exact(y);
        } else {
            outp[(long)n * DD + lane] = gelu_exact(y + identity[(long)n * DD + lane]);
        }
    }
}

// ---------- launch ----------
extern "C" void kernel_launch(void* const* d_in, const int* in_sizes, int n_in,
                              void* d_out, int out_size, void* d_ws, size_t ws_size,
                              hipStream_t stream) {
    (void)in_sizes; (void)n_in; (void)out_size; (void)ws_size;

    const float* h     = (const float*)d_in[0];
    const int*   ei    = (const int*)d_in[1];
    const float* ea    = (const float*)d_in[2];
    const float* g1Wl  = (const float*)d_in[3];
    const float* g1bl  = (const float*)d_in[4];
    const float* g1Wr  = (const float*)d_in[5];
    const float* g1br  = (const float*)d_in[6];
    const float* g1We  = (const float*)d_in[7];
    const float* g1att = (const float*)d_in[8];
    const float* g1bias= (const float*)d_in[9];
    const float* ln1g  = (const float*)d_in[10];
    const float* ln1b  = (const float*)d_in[11];
    const float* g2Wl  = (const float*)d_in[12];
    const float* g2bl  = (const float*)d_in[13];
    const float* g2Wr  = (const float*)d_in[14];
    const float* g2br  = (const float*)d_in[15];
    const float* g2We  = (const float*)d_in[16];
    const float* g2att = (const float*)d_in[17];
    const float* g2bias= (const float*)d_in[18];
    const float* ln2g  = (const float*)d_in[19];
    const float* ln2b  = (const float*)d_in[20];

    float* out = (float*)d_out;

    // workspace layout (4-byte units), total ~119 MB
    float* ws = (float*)d_ws;
    size_t o = 0;
    float* xl     = ws + o;        o += 12800000;   // N*256
    float* xr     = ws + o;        o += 12800000;   // N*256
    float* x1     = ws + o;        o += 3200000;    // N*64
    int*   rowptr = (int*)(ws + o); o += 50004;     // N+1
    int*   deg    = (int*)(ws + o); o += 50000;
    int*   cursor = (int*)(ws + o); o += 50000;
    int*   bsum   = (int*)(ws + o); o += 256;
    int*   srcs   = (int*)(ws + o); o += 400000;
    int*   eidx   = (int*)(ws + o); o += 400000;

    const int GEMM_BLOCKS  = (NN + 31) / 32;    // 1563
    const int SCAN_BLOCKS  = (NN + 255) / 256;  // 196
    const int EDGE_BLOCKS  = (EE + 255) / 256;  // 1563

    // ----- CSR build (once; graph identical for both layers) -----
    fill_u32<<<256, 256, 0, stream>>>((unsigned*)deg, 0u, NN);
    hist_k<<<EDGE_BLOCKS, 256, 0, stream>>>(ei, deg);
    scan1_k<<<SCAN_BLOCKS, 256, 0, stream>>>(deg, rowptr, bsum);
    scan2_k<<<1, 256, 0, stream>>>(bsum, SCAN_BLOCKS);
    scan3_k<<<SCAN_BLOCKS, 256, 0, stream>>>(rowptr, bsum, cursor);
    scatter_k<<<EDGE_BLOCKS, 256, 0, stream>>>(ei, cursor, srcs, eidx);

    // ----- layer 1 -----
    gemm_node<<<GEMM_BLOCKS, 256, 0, stream>>>(h, g1Wl, g1bl, xl, NN);
    gemm_node<<<GEMM_BLOCKS, 256, 0, stream>>>(h, g1Wr, g1br, xr, NN);
    gat_fused_k<<<GAT_BLOCKS, 256, 0, stream>>>(rowptr, srcs, eidx, ea, g1We, g1att,
                                                xl, xr, g1bias, ln1g, ln1b, h, x1, out, 0);

    // ----- layer 2 -----
    gemm_node<<<GEMM_BLOCKS, 256, 0, stream>>>(x1, g2Wl, g2bl, xl, NN);
    gemm_node<<<GEMM_BLOCKS, 256, 0, stream>>>(x1, g2Wr, g2br, xr, NN);
    gat_fused_k<<<GAT_BLOCKS, 256, 0, stream>>>(rowptr, srcs, eidx, ea, g2We, g2att,
                                                xl, xr, g2bias, ln2g, ln2b, h, x1, out, 1);
}

// Round 4
// 858.313 us; speedup vs baseline: 2.0644x; 1.2953x over previous
//
#include <hip/hip_runtime.h>
#include <math.h>

// Problem constants (fixed by reference setup_inputs)
#define NN  50000
#define EE  400000
#define DD  64
#define HH  4
#define HC  256      // H * C
#define EDD 16

#define GAT_BLOCKS 3200   // 12800 waves, ~4 nodes/wave

// wave64 butterfly sum — all lanes end with the total
__device__ __forceinline__ float wsum(float v) {
#pragma unroll
    for (int m = 32; m > 0; m >>= 1) v += __shfl_xor(v, m, 64);
    return v;
}

__device__ __forceinline__ float gelu_exact(float x) {
    return 0.5f * x * (1.0f + erff(x * 0.70710678118654752440f));
}

// ---------- fills ----------
__global__ void fill_u32(unsigned* __restrict__ p, unsigned v, int n) {
    int i = blockIdx.x * blockDim.x + threadIdx.x;
    int s = gridDim.x * blockDim.x;
    for (; i < n; i += s) p[i] = v;
}

// ---------- CSR build (counting sort by dst; once per call, shared by both layers) ----------
__global__ void hist_k(const int* __restrict__ ei, int* __restrict__ deg) {
    int e = blockIdx.x * 256 + threadIdx.x;
    if (e < EE) atomicAdd(&deg[ei[EE + e]], 1);
}

__global__ void scan1_k(const int* __restrict__ deg, int* __restrict__ rowptr,
                        int* __restrict__ bsum) {
    __shared__ int s[256];
    int t = threadIdx.x, i = blockIdx.x * 256 + t;
    int v = (i < NN) ? deg[i] : 0;
    s[t] = v; __syncthreads();
    for (int o = 1; o < 256; o <<= 1) {
        int u = (t >= o) ? s[t - o] : 0;
        __syncthreads();
        s[t] += u;
        __syncthreads();
    }
    if (i < NN) rowptr[i] = s[t] - v;       // block-local exclusive
    if (t == 255) bsum[blockIdx.x] = s[255];
}
__global__ void scan2_k(int* __restrict__ bsum, int nb) {
    __shared__ int s[256];
    int t = threadIdx.x;
    int v = (t < nb) ? bsum[t] : 0;
    s[t] = v; __syncthreads();
    for (int o = 1; o < 256; o <<= 1) {
        int u = (t >= o) ? s[t - o] : 0;
        __syncthreads();
        s[t] += u;
        __syncthreads();
    }
    if (t < nb) bsum[t] = s[t] - v;         // exclusive over blocks
}
__global__ void scan3_k(int* __restrict__ rowptr, const int* __restrict__ bsum,
                        int* __restrict__ cursor) {
    int i = blockIdx.x * 256 + threadIdx.x;
    if (i < NN) {
        int r = rowptr[i] + bsum[blockIdx.x];
        rowptr[i] = r;
        cursor[i] = r;
    }
    if (i == 0) rowptr[NN] = EE;
}
__global__ void scatter_k(const int* __restrict__ ei, int* __restrict__ cursor,
                          int* __restrict__ srcs, int* __restrict__ eidx) {
    int e = blockIdx.x * 256 + threadIdx.x;
    if (e >= EE) return;
    int dst = ei[EE + e];
    int pos = atomicAdd(&cursor[dst], 1);
    srcs[pos] = ei[e];
    eidx[pos] = e;
}

// ---------- node GEMM: Y[N,256] = X[N,64] @ W[64,256] + b ----------
// W column in 64 VGPRs per thread; X rows are block-uniform -> scalar loads.
// No LDS, no broadcast reads.
__global__ __launch_bounds__(256) void gemm_node(
    const float* __restrict__ X, const float* __restrict__ W,
    const float* __restrict__ b, float* __restrict__ Y)
{
    const int col  = threadIdx.x;
    const int base = blockIdx.x * 32;

    float wk[64];
#pragma unroll
    for (int k = 0; k < 64; k++) wk[k] = W[k * 256 + col];
    const float bb = b[col];

#pragma unroll 2
    for (int r = 0; r < 32; r++) {
        const int row = base + r;
        const int rr  = (row < NN) ? row : (NN - 1);   // clamp loads, guard store
        const float* __restrict__ xrow = X + (long)rr * 64;
        float a0 = 0.f, a1 = 0.f;
#pragma unroll
        for (int k = 0; k < 64; k += 2) {
            a0 = fmaf(xrow[k],     wk[k],     a0);
            a1 = fmaf(xrow[k + 1], wk[k + 1], a1);
        }
        if (row < NN) Y[(long)row * 256 + col] = a0 + a1 + bb;
    }
}

// ---------- fused GAT aggregation: one wave per dst node ----------
// online softmax per head, aggregation + LN + GELU in registers. No LDS.
// Edge metadata (src, eidx, edge_attr) is wave-uniform -> scalar loads.
// 2-stage manual pipeline (A/B register sets) hides gather latency.
__global__ __launch_bounds__(256, 3) void gat_fused_k(
    const int* __restrict__ rowptr, const int* __restrict__ srcs,
    const int* __restrict__ eidx, const float* __restrict__ ea,
    const float* __restrict__ We, const float* __restrict__ att,
    const float* __restrict__ xl, const float* __restrict__ xr,
    const float* __restrict__ bias, const float* __restrict__ lng,
    const float* __restrict__ lnb, const float* __restrict__ identity,
    float* __restrict__ x1out, float* __restrict__ outp, int mode)
{
    const int lane = threadIdx.x & 63;
    const int wid  = blockIdx.x * 4 + (threadIdx.x >> 6);

    // this lane's We column (per head) and att entry — registers
    float wreg[HH][EDD];
#pragma unroll
    for (int h = 0; h < HH; h++)
#pragma unroll
        for (int k = 0; k < EDD; k++) wreg[h][k] = We[k * HC + h * 64 + lane];
    float attr[HH];
#pragma unroll
    for (int h = 0; h < HH; h++) attr[h] = att[h * 64 + lane];
    const float bia = bias[lane];
    const float lg  = lng[lane];
    const float lb  = lnb[lane];

    for (int n = wid; n < NN; n += GAT_BLOCKS * 4) {
        const int p0 = __builtin_amdgcn_readfirstlane(rowptr[n]);
        const int p1 = __builtin_amdgcn_readfirstlane(rowptr[n + 1]);

        float xrv[HH];
#pragma unroll
        for (int h = 0; h < HH; h++) xrv[h] = xr[(long)n * HC + h * 64 + lane];

        float m[HH], l[HH], acc[HH];
#pragma unroll
        for (int h = 0; h < HH; h++) { m[h] = -INFINITY; l[h] = 0.f; acc[h] = 0.f; }

        // ---- A/B pipelined edge loop ----
        int   srcA = 0, srcB = 0;
        float eaA[EDD], eaB[EDD], xlvA[HH], xlvB[HH];

#define PRELOAD(S, EA, XLV, p)                                                 \
        {                                                                      \
            S = __builtin_amdgcn_readfirstlane(srcs[p]);                       \
            const int _e = __builtin_amdgcn_readfirstlane(eidx[p]);            \
            const float* __restrict__ _eap = ea + (long)_e * EDD;              \
            _Pragma("unroll")                                                  \
            for (int k = 0; k < EDD; k++) EA[k] = _eap[k];                     \
            _Pragma("unroll")                                                  \
            for (int h = 0; h < HH; h++)                                       \
                XLV[h] = xl[(long)S * HC + h * 64 + lane];                     \
        }

#define COMPUTE(S, EA, XLV)                                                    \
        {                                                                      \
            _Pragma("unroll")                                                  \
            for (int h = 0; h < HH; h++) {                                     \
                float ez = 0.f;                                                \
                _Pragma("unroll")                                              \
                for (int k = 0; k < EDD; k++)                                  \
                    ez = fmaf(EA[k], wreg[h][k], ez);                          \
                float s = XLV[h] + xrv[h] + ez;                                \
                s = (s > 0.f) ? s : 0.2f * s;                                  \
                const float pl = wsum(s * attr[h]);                            \
                const float mn = fmaxf(m[h], pl);                              \
                const float c  = expf(m[h] - mn);                              \
                const float w  = expf(pl - mn);                                \
                l[h]   = l[h] * c + w;                                         \
                acc[h] = acc[h] * c + w * XLV[h];                              \
                m[h]   = mn;                                                   \
            }                                                                  \
        }

        int p = p0;
        if (p < p1) PRELOAD(srcA, eaA, xlvA, p);
        while (p < p1) {
            if (p + 1 < p1) PRELOAD(srcB, eaB, xlvB, p + 1);
            COMPUTE(srcA, eaA, xlvA);
            p++;
            if (p >= p1) break;
            if (p + 1 < p1) PRELOAD(srcA, eaA, xlvA, p + 1);
            COMPUTE(srcB, eaB, xlvB);
            p++;
        }
#undef PRELOAD
#undef COMPUTE

        // epilogue: head mean + bias + LN + GELU (+ residual)
        float v = 0.f;
#pragma unroll
        for (int h = 0; h < HH; h++) v += acc[h] / (l[h] + 1e-16f);
        v = v * 0.25f + bia;

        const float mu  = wsum(v) * (1.0f / 64.0f);
        const float d   = v - mu;
        const float var = wsum(d * d) * (1.0f / 64.0f);
        const float y   = d * rsqrtf(var + 1e-5f) * lg + lb;

        if (mode == 0) {
            x1out[(long)n * DD + lane] = gelu_exact(y);
        } else {
            outp[(long)n * DD + lane] = gelu_exact(y + identity[(long)n * DD + lane]);
        }
    }
}

// ---------- launch ----------
extern "C" void kernel_launch(void* const* d_in, const int* in_sizes, int n_in,
                              void* d_out, int out_size, void* d_ws, size_t ws_size,
                              hipStream_t stream) {
    (void)in_sizes; (void)n_in; (void)out_size; (void)ws_size;

    const float* h     = (const float*)d_in[0];
    const int*   ei    = (const int*)d_in[1];
    const float* ea    = (const float*)d_in[2];
    const float* g1Wl  = (const float*)d_in[3];
    const float* g1bl  = (const float*)d_in[4];
    const float* g1Wr  = (const float*)d_in[5];
    const float* g1br  = (const float*)d_in[6];
    const float* g1We  = (const float*)d_in[7];
    const float* g1att = (const float*)d_in[8];
    const float* g1bias= (const float*)d_in[9];
    const float* ln1g  = (const float*)d_in[10];
    const float* ln1b  = (const float*)d_in[11];
    const float* g2Wl  = (const float*)d_in[12];
    const float* g2bl  = (const float*)d_in[13];
    const float* g2Wr  = (const float*)d_in[14];
    const float* g2br  = (const float*)d_in[15];
    const float* g2We  = (const float*)d_in[16];
    const float* g2att = (const float*)d_in[17];
    const float* g2bias= (const float*)d_in[18];
    const float* ln2g  = (const float*)d_in[19];
    const float* ln2b  = (const float*)d_in[20];

    float* out = (float*)d_out;

    // workspace layout (4-byte units)
    float* ws = (float*)d_ws;
    size_t o = 0;
    float* xl     = ws + o;         o += 12800000;   // N*256
    float* xr     = ws + o;         o += 12800000;   // N*256
    float* x1     = ws + o;         o += 3200000;    // N*64
    int*   rowptr = (int*)(ws + o); o += 50004;      // N+1
    int*   deg    = (int*)(ws + o); o += 50000;
    int*   cursor = (int*)(ws + o); o += 50000;
    int*   bsum   = (int*)(ws + o); o += 256;
    int*   srcs   = (int*)(ws + o); o += 400000;
    int*   eidx   = (int*)(ws + o); o += 400000;

    const int GEMM_BLOCKS  = (NN + 31) / 32;    // 1563
    const int SCAN_BLOCKS  = (NN + 255) / 256;  // 196
    const int EDGE_BLOCKS  = (EE + 255) / 256;  // 1563

    // ----- CSR build (once; graph identical for both layers) -----
    fill_u32<<<256, 256, 0, stream>>>((unsigned*)deg, 0u, NN);
    hist_k<<<EDGE_BLOCKS, 256, 0, stream>>>(ei, deg);
    scan1_k<<<SCAN_BLOCKS, 256, 0, stream>>>(deg, rowptr, bsum);
    scan2_k<<<1, 256, 0, stream>>>(bsum, SCAN_BLOCKS);
    scan3_k<<<SCAN_BLOCKS, 256, 0, stream>>>(rowptr, bsum, cursor);
    scatter_k<<<EDGE_BLOCKS, 256, 0, stream>>>(ei, cursor, srcs, eidx);

    // ----- layer 1 -----
    gemm_node<<<GEMM_BLOCKS, 256, 0, stream>>>(h, g1Wl, g1bl, xl);
    gemm_node<<<GEMM_BLOCKS, 256, 0, stream>>>(h, g1Wr, g1br, xr);
    gat_fused_k<<<GAT_BLOCKS, 256, 0, stream>>>(rowptr, srcs, eidx, ea, g1We, g1att,
                                                xl, xr, g1bias, ln1g, ln1b, h, x1, out, 0);

    // ----- layer 2 -----
    gemm_node<<<GEMM_BLOCKS, 256, 0, stream>>>(x1, g2Wl, g2bl, xl);
    gemm_node<<<GEMM_BLOCKS, 256, 0, stream>>>(x1, g2Wr, g2br, xr);
    gat_fused_k<<<GAT_BLOCKS, 256, 0, stream>>>(rowptr, srcs, eidx, ea, g2We, g2att,
                                                xl, xr, g2bias, ln2g, ln2b, h, x1, out, 1);
}

// Round 5
// 786.204 us; speedup vs baseline: 2.2537x; 1.0917x over previous
//
#include <hip/hip_runtime.h>
#include <math.h>

// Problem constants (fixed by reference setup_inputs)
#define NN  50000
#define EE  400000
#define DD  64
#define HH  4
#define HC  256      // H * C
#define EDD 16

#define GAT_BLOCKS 3200   // 12800 waves, ~4 nodes/wave

// wave64 butterfly sum — all lanes end with the total
__device__ __forceinline__ float wsum(float v) {
#pragma unroll
    for (int m = 32; m > 0; m >>= 1) v += __shfl_xor(v, m, 64);
    return v;
}

__device__ __forceinline__ float gelu_exact(float x) {
    return 0.5f * x * (1.0f + erff(x * 0.70710678118654752440f));
}

// fast exp via v_exp_f32 (2^x): exp(x) = 2^(x*log2e). exp2(-inf)=0 preserved.
__device__ __forceinline__ float fast_exp(float x) {
    return __builtin_amdgcn_exp2f(x * 1.44269504088896340736f);
}

// ---------- fills ----------
__global__ void fill_u32(unsigned* __restrict__ p, unsigned v, int n) {
    int i = blockIdx.x * blockDim.x + threadIdx.x;
    int s = gridDim.x * blockDim.x;
    for (; i < n; i += s) p[i] = v;
}

// ---------- CSR build (counting sort by dst; once per call, shared by both layers) ----------
__global__ void hist_k(const int* __restrict__ ei, int* __restrict__ deg) {
    int e = blockIdx.x * 256 + threadIdx.x;
    if (e < EE) atomicAdd(&deg[ei[EE + e]], 1);
}

__global__ void scan1_k(const int* __restrict__ deg, int* __restrict__ rowptr,
                        int* __restrict__ bsum) {
    __shared__ int s[256];
    int t = threadIdx.x, i = blockIdx.x * 256 + t;
    int v = (i < NN) ? deg[i] : 0;
    s[t] = v; __syncthreads();
    for (int o = 1; o < 256; o <<= 1) {
        int u = (t >= o) ? s[t - o] : 0;
        __syncthreads();
        s[t] += u;
        __syncthreads();
    }
    if (i < NN) rowptr[i] = s[t] - v;       // block-local exclusive
    if (t == 255) bsum[blockIdx.x] = s[255];
}
__global__ void scan2_k(int* __restrict__ bsum, int nb) {
    __shared__ int s[256];
    int t = threadIdx.x;
    int v = (t < nb) ? bsum[t] : 0;
    s[t] = v; __syncthreads();
    for (int o = 1; o < 256; o <<= 1) {
        int u = (t >= o) ? s[t - o] : 0;
        __syncthreads();
        s[t] += u;
        __syncthreads();
    }
    if (t < nb) bsum[t] = s[t] - v;         // exclusive over blocks
}
__global__ void scan3_k(int* __restrict__ rowptr, const int* __restrict__ bsum,
                        int* __restrict__ cursor) {
    int i = blockIdx.x * 256 + threadIdx.x;
    if (i < NN) {
        int r = rowptr[i] + bsum[blockIdx.x];
        rowptr[i] = r;
        cursor[i] = r;
    }
    if (i == 0) rowptr[NN] = EE;
}
__global__ void scatter_k(const int* __restrict__ ei, int* __restrict__ cursor,
                          int* __restrict__ srcs, int* __restrict__ eidx) {
    int e = blockIdx.x * 256 + threadIdx.x;
    if (e >= EE) return;
    int dst = ei[EE + e];
    int pos = atomicAdd(&cursor[dst], 1);
    srcs[pos] = ei[e];
    eidx[pos] = e;
}

// ---------- node GEMM: Y[N,256] = X[N,64] @ W[64,256] + b ----------
// W column in 64 VGPRs per thread; X rows are block-uniform -> scalar loads.
__global__ __launch_bounds__(256) void gemm_node(
    const float* __restrict__ X, const float* __restrict__ W,
    const float* __restrict__ b, float* __restrict__ Y)
{
    const int col  = threadIdx.x;
    const int base = blockIdx.x * 32;

    float wk[64];
#pragma unroll
    for (int k = 0; k < 64; k++) wk[k] = W[k * 256 + col];
    const float bb = b[col];

#pragma unroll 2
    for (int r = 0; r < 32; r++) {
        const int row = base + r;
        const int rr  = (row < NN) ? row : (NN - 1);   // clamp loads, guard store
        const float* __restrict__ xrow = X + (long)rr * 64;
        float a0 = 0.f, a1 = 0.f;
#pragma unroll
        for (int k = 0; k < 64; k += 2) {
            a0 = fmaf(xrow[k],     wk[k],     a0);
            a1 = fmaf(xrow[k + 1], wk[k + 1], a1);
        }
        if (row < NN) Y[(long)row * 256 + col] = a0 + a1 + bb;
    }
}

// ---------- fused GAT aggregation: one wave per dst node ----------
// online softmax per head, aggregation + LN + GELU in registers. No LDS.
// Edge metadata (src, eidx, edge_attr) is wave-uniform -> scalar loads.
// wreg pinned in VGPRs via asm (blocks rematerialization of We loads).
__global__ __launch_bounds__(256, 3) void gat_fused_k(
    const int* __restrict__ rowptr, const int* __restrict__ srcs,
    const int* __restrict__ eidx, const float* __restrict__ ea,
    const float* __restrict__ We, const float* __restrict__ att,
    const float* __restrict__ xl, const float* __restrict__ xr,
    const float* __restrict__ bias, const float* __restrict__ lng,
    const float* __restrict__ lnb, const float* __restrict__ identity,
    float* __restrict__ x1out, float* __restrict__ outp, int mode)
{
    const int lane = threadIdx.x & 63;
    const int wid  = blockIdx.x * 4 + (threadIdx.x >> 6);

    // this lane's We column (per head) and att entry — pinned registers
    float wreg[HH][EDD];
#pragma unroll
    for (int h = 0; h < HH; h++)
#pragma unroll
        for (int k = 0; k < EDD; k++) wreg[h][k] = We[k * HC + h * 64 + lane];
    float attr[HH];
#pragma unroll
    for (int h = 0; h < HH; h++) attr[h] = att[h * 64 + lane];
    // opaque defs: compiler cannot rematerialize the loads above
#pragma unroll
    for (int h = 0; h < HH; h++) {
        asm volatile("" : "+v"(attr[h]));
#pragma unroll
        for (int k = 0; k < EDD; k++) asm volatile("" : "+v"(wreg[h][k]));
    }
    const float bia = bias[lane];
    const float lg  = lng[lane];
    const float lb  = lnb[lane];

    for (int n = wid; n < NN; n += GAT_BLOCKS * 4) {
        const int p0 = __builtin_amdgcn_readfirstlane(rowptr[n]);
        const int p1 = __builtin_amdgcn_readfirstlane(rowptr[n + 1]);

        float xrv[HH];
#pragma unroll
        for (int h = 0; h < HH; h++) xrv[h] = xr[(long)n * HC + h * 64 + lane];

        float m[HH], l[HH], acc[HH];
#pragma unroll
        for (int h = 0; h < HH; h++) { m[h] = -INFINITY; l[h] = 0.f; acc[h] = 0.f; }

        // ---- A/B pipelined edge loop ----
        int   srcA = 0, srcB = 0;
        float eaA[EDD], eaB[EDD], xlvA[HH], xlvB[HH];

#define PRELOAD(S, EA, XLV, p)                                                 \
        {                                                                      \
            S = __builtin_amdgcn_readfirstlane(srcs[p]);                       \
            const int _e = __builtin_amdgcn_readfirstlane(eidx[p]);            \
            const float* __restrict__ _eap = ea + (long)_e * EDD;              \
            _Pragma("unroll")                                                  \
            for (int k = 0; k < EDD; k++) EA[k] = _eap[k];                     \
            _Pragma("unroll")                                                  \
            for (int h = 0; h < HH; h++)                                       \
                XLV[h] = xl[(long)S * HC + h * 64 + lane];                     \
        }

#define COMPUTE(S, EA, XLV)                                                    \
        {                                                                      \
            _Pragma("unroll")                                                  \
            for (int h = 0; h < HH; h++) {                                     \
                float ez = 0.f;                                                \
                _Pragma("unroll")                                              \
                for (int k = 0; k < EDD; k++)                                  \
                    ez = fmaf(EA[k], wreg[h][k], ez);                          \
                float s = XLV[h] + xrv[h] + ez;                                \
                s = (s > 0.f) ? s : 0.2f * s;                                  \
                const float pl = wsum(s * attr[h]);                            \
                const float mn = fmaxf(m[h], pl);                              \
                const float c  = fast_exp(m[h] - mn);                          \
                const float w  = fast_exp(pl - mn);                            \
                l[h]   = l[h] * c + w;                                         \
                acc[h] = acc[h] * c + w * XLV[h];                              \
                m[h]   = mn;                                                   \
            }                                                                  \
        }

        int p = p0;
        if (p < p1) PRELOAD(srcA, eaA, xlvA, p);
        while (p < p1) {
            if (p + 1 < p1) PRELOAD(srcB, eaB, xlvB, p + 1);
            COMPUTE(srcA, eaA, xlvA);
            p++;
            if (p >= p1) break;
            if (p + 1 < p1) PRELOAD(srcA, eaA, xlvA, p + 1);
            COMPUTE(srcB, eaB, xlvB);
            p++;
        }
#undef PRELOAD
#undef COMPUTE

        // epilogue: head mean + bias + LN + GELU (+ residual)
        float v = 0.f;
#pragma unroll
        for (int h = 0; h < HH; h++) v += acc[h] / (l[h] + 1e-16f);
        v = v * 0.25f + bia;

        const float mu  = wsum(v) * (1.0f / 64.0f);
        const float d   = v - mu;
        const float var = wsum(d * d) * (1.0f / 64.0f);
        const float y   = d * rsqrtf(var + 1e-5f) * lg + lb;

        if (mode == 0) {
            x1out[(long)n * DD + lane] = gelu_exact(y);
        } else {
            outp[(long)n * DD + lane] = gelu_exact(y + identity[(long)n * DD + lane]);
        }
    }
}

// ---------- launch ----------
extern "C" void kernel_launch(void* const* d_in, const int* in_sizes, int n_in,
                              void* d_out, int out_size, void* d_ws, size_t ws_size,
                              hipStream_t stream) {
    (void)in_sizes; (void)n_in; (void)out_size; (void)ws_size;

    const float* h     = (const float*)d_in[0];
    const int*   ei    = (const int*)d_in[1];
    const float* ea    = (const float*)d_in[2];
    const float* g1Wl  = (const float*)d_in[3];
    const float* g1bl  = (const float*)d_in[4];
    const float* g1Wr  = (const float*)d_in[5];
    const float* g1br  = (const float*)d_in[6];
    const float* g1We  = (const float*)d_in[7];
    const float* g1att = (const float*)d_in[8];
    const float* g1bias= (const float*)d_in[9];
    const float* ln1g  = (const float*)d_in[10];
    const float* ln1b  = (const float*)d_in[11];
    const float* g2Wl  = (const float*)d_in[12];
    const float* g2bl  = (const float*)d_in[13];
    const float* g2Wr  = (const float*)d_in[14];
    const float* g2br  = (const float*)d_in[15];
    const float* g2We  = (const float*)d_in[16];
    const float* g2att = (const float*)d_in[17];
    const float* g2bias= (const float*)d_in[18];
    const float* ln2g  = (const float*)d_in[19];
    const float* ln2b  = (const float*)d_in[20];

    float* out = (float*)d_out;

    // workspace layout (4-byte units)
    float* ws = (float*)d_ws;
    size_t o = 0;
    float* xl     = ws + o;         o += 12800000;   // N*256
    float* xr     = ws + o;         o += 12800000;   // N*256
    float* x1     = ws + o;         o += 3200000;    // N*64
    int*   rowptr = (int*)(ws + o); o += 50004;      // N+1
    int*   deg    = (int*)(ws + o); o += 50000;
    int*   cursor = (int*)(ws + o); o += 50000;
    int*   bsum   = (int*)(ws + o); o += 256;
    int*   srcs   = (int*)(ws + o); o += 400000;
    int*   eidx   = (int*)(ws + o); o += 400000;

    const int GEMM_BLOCKS  = (NN + 31) / 32;    // 1563
    const int SCAN_BLOCKS  = (NN + 255) / 256;  // 196
    const int EDGE_BLOCKS  = (EE + 255) / 256;  // 1563

    // ----- CSR build (once; graph identical for both layers) -----
    fill_u32<<<256, 256, 0, stream>>>((unsigned*)deg, 0u, NN);
    hist_k<<<EDGE_BLOCKS, 256, 0, stream>>>(ei, deg);
    scan1_k<<<SCAN_BLOCKS, 256, 0, stream>>>(deg, rowptr, bsum);
    scan2_k<<<1, 256, 0, stream>>>(bsum, SCAN_BLOCKS);
    scan3_k<<<SCAN_BLOCKS, 256, 0, stream>>>(rowptr, bsum, cursor);
    scatter_k<<<EDGE_BLOCKS, 256, 0, stream>>>(ei, cursor, srcs, eidx);

    // ----- layer 1 -----
    gemm_node<<<GEMM_BLOCKS, 256, 0, stream>>>(h, g1Wl, g1bl, xl);
    gemm_node<<<GEMM_BLOCKS, 256, 0, stream>>>(h, g1Wr, g1br, xr);
    gat_fused_k<<<GAT_BLOCKS, 256, 0, stream>>>(rowptr, srcs, eidx, ea, g1We, g1att,
                                                xl, xr, g1bias, ln1g, ln1b, h, x1, out, 0);

    // ----- layer 2 -----
    gemm_node<<<GEMM_BLOCKS, 256, 0, stream>>>(x1, g2Wl, g2bl, xl);
    gemm_node<<<GEMM_BLOCKS, 256, 0, stream>>>(x1, g2Wr, g2br, xr);
    gat_fused_k<<<GAT_BLOCKS, 256, 0, stream>>>(rowptr, srcs, eidx, ea, g2We, g2att,
                                                xl, xr, g2bias, ln2g, ln2b, h, x1, out, 1);
}

// Round 6
// 722.854 us; speedup vs baseline: 2.4512x; 1.0876x over previous
//
#include <hip/hip_runtime.h>
#include <math.h>

// Problem constants (fixed by reference setup_inputs)
#define NN  50000
#define EE  400000
#define DD  64
#define HH  4
#define HC  256      // H * C
#define EDD 16

// wave64 butterfly sum — all lanes end with the total
__device__ __forceinline__ float wsum(float v) {
#pragma unroll
    for (int m = 32; m > 0; m >>= 1) v += __shfl_xor(v, m, 64);
    return v;
}

__device__ __forceinline__ float gelu_exact(float x) {
    return 0.5f * x * (1.0f + erff(x * 0.70710678118654752440f));
}

// fast exp via v_exp_f32 (2^x): exp(x) = 2^(x*log2e). exp2(-inf)=0 preserved.
__device__ __forceinline__ float fast_exp(float x) {
    return __builtin_amdgcn_exp2f(x * 1.44269504088896340736f);
}

// ---------- fills ----------
__global__ void fill_u32(unsigned* __restrict__ p, unsigned v, int n) {
    int i = blockIdx.x * blockDim.x + threadIdx.x;
    int s = gridDim.x * blockDim.x;
    for (; i < n; i += s) p[i] = v;
}

// ---------- CSR build (counting sort by dst; once per call, shared by both layers) ----------
__global__ void hist_k(const int* __restrict__ ei, int* __restrict__ deg) {
    int e = blockIdx.x * 256 + threadIdx.x;
    if (e < EE) atomicAdd(&deg[ei[EE + e]], 1);
}

__global__ void scan1_k(const int* __restrict__ deg, int* __restrict__ rowptr,
                        int* __restrict__ bsum) {
    __shared__ int s[256];
    int t = threadIdx.x, i = blockIdx.x * 256 + t;
    int v = (i < NN) ? deg[i] : 0;
    s[t] = v; __syncthreads();
    for (int o = 1; o < 256; o <<= 1) {
        int u = (t >= o) ? s[t - o] : 0;
        __syncthreads();
        s[t] += u;
        __syncthreads();
    }
    if (i < NN) rowptr[i] = s[t] - v;       // block-local exclusive
    if (t == 255) bsum[blockIdx.x] = s[255];
}
__global__ void scan2_k(int* __restrict__ bsum, int nb) {
    __shared__ int s[256];
    int t = threadIdx.x;
    int v = (t < nb) ? bsum[t] : 0;
    s[t] = v; __syncthreads();
    for (int o = 1; o < 256; o <<= 1) {
        int u = (t >= o) ? s[t - o] : 0;
        __syncthreads();
        s[t] += u;
        __syncthreads();
    }
    if (t < nb) bsum[t] = s[t] - v;         // exclusive over blocks
}
__global__ void scan3_k(int* __restrict__ rowptr, const int* __restrict__ bsum,
                        int* __restrict__ cursor) {
    int i = blockIdx.x * 256 + threadIdx.x;
    if (i < NN) {
        int r = rowptr[i] + bsum[blockIdx.x];
        rowptr[i] = r;
        cursor[i] = r;
    }
    if (i == 0) rowptr[NN] = EE;
}
// scatter srcs AND edge_attr into CSR order (drops eidx indirection from hot loop)
__global__ void scatter_k(const int* __restrict__ ei, int* __restrict__ cursor,
                          const float* __restrict__ ea,
                          int* __restrict__ srcs, float* __restrict__ ea_s) {
    int e = blockIdx.x * 256 + threadIdx.x;
    if (e >= EE) return;
    int dst = ei[EE + e];
    int pos = atomicAdd(&cursor[dst], 1);
    srcs[pos] = ei[e];
    const float4* s4 = (const float4*)(ea + (long)e * EDD);
    float4* d4 = (float4*)(ea_s + (long)pos * EDD);
    d4[0] = s4[0]; d4[1] = s4[1]; d4[2] = s4[2]; d4[3] = s4[3];
}

// ---------- node GEMM: Y[N,256] = X[N,64] @ W[64,256] + b ----------
// W column in 64 VGPRs per thread; X rows are block-uniform -> scalar loads.
__global__ __launch_bounds__(256) void gemm_node(
    const float* __restrict__ X, const float* __restrict__ W,
    const float* __restrict__ b, float* __restrict__ Y)
{
    const int col  = threadIdx.x;
    const int base = blockIdx.x * 32;

    float wk[64];
#pragma unroll
    for (int k = 0; k < 64; k++) wk[k] = W[k * 256 + col];
    const float bb = b[col];

#pragma unroll 2
    for (int r = 0; r < 32; r++) {
        const int row = base + r;
        const int rr  = (row < NN) ? row : (NN - 1);   // clamp loads, guard store
        const float* __restrict__ xrow = X + (long)rr * 64;
        float a0 = 0.f, a1 = 0.f, a2 = 0.f, a3 = 0.f;
#pragma unroll
        for (int k = 0; k < 64; k += 4) {
            a0 = fmaf(xrow[k],     wk[k],     a0);
            a1 = fmaf(xrow[k + 1], wk[k + 1], a1);
            a2 = fmaf(xrow[k + 2], wk[k + 2], a2);
            a3 = fmaf(xrow[k + 3], wk[k + 3], a3);
        }
        if (row < NN) Y[(long)row * 256 + col] = (a0 + a1) + (a2 + a3) + bb;
    }
}

// ---------- fused GAT aggregation: one wave per dst node ----------
// Lane layout: head h = lane>>4, channel quad cb = (lane&15)*4.
// Per-head logit reduces over 16 lanes (4 butterfly steps, all heads at once).
// xl gather = one dwordx4 per lane. ea pre-sorted -> sequential scalar loads.
__global__ __launch_bounds__(256, 3) void gat_fused_k(
    const int* __restrict__ rowptr, const int* __restrict__ srcs,
    const float* __restrict__ ea_s,
    const float* __restrict__ We, const float* __restrict__ att,
    const float* __restrict__ xl, const float* __restrict__ xr,
    const float* __restrict__ bias, const float* __restrict__ lng,
    const float* __restrict__ lnb, const float* __restrict__ identity,
    float* __restrict__ x1out, float* __restrict__ outp, int mode)
{
    const int lane = threadIdx.x & 63;
    const int n    = blockIdx.x * 4 + (threadIdx.x >> 6);   // 12500*4 = 50000 exactly
    const int gc   = ((lane >> 4) << 6) + ((lane & 15) << 2);  // h*64 + q*4
    const int cb   = (lane & 15) << 2;                          // channel quad

    // this lane's We column (its head, its 4 channels) — pinned registers
    float wreg[EDD][4];
#pragma unroll
    for (int k = 0; k < EDD; k++) {
        const float4 w4 = *(const float4*)(We + k * HC + gc);
        wreg[k][0] = w4.x; wreg[k][1] = w4.y; wreg[k][2] = w4.z; wreg[k][3] = w4.w;
    }
#pragma unroll
    for (int k = 0; k < EDD; k++)
#pragma unroll
        for (int j = 0; j < 4; j++) asm volatile("" : "+v"(wreg[k][j]));

    const float4 a4 = *(const float4*)(att + gc);

    const int p0 = __builtin_amdgcn_readfirstlane(rowptr[n]);
    const int p1 = __builtin_amdgcn_readfirstlane(rowptr[n + 1]);

    const float4 xrv = *(const float4*)(xr + (long)n * HC + gc);

    float m = -INFINITY, l = 0.f;
    float ac0 = 0.f, ac1 = 0.f, ac2 = 0.f, ac3 = 0.f;

    // ---- A/B pipelined edge loop ----
    float4 xlvA, xlvB;
    float  eaA[EDD], eaB[EDD];

#define PRELOAD(EA, XLV, p)                                                    \
    {                                                                          \
        const int _s = __builtin_amdgcn_readfirstlane(srcs[p]);                \
        const float* __restrict__ _eap = ea_s + (long)(p) * EDD;               \
        _Pragma("unroll")                                                      \
        for (int k = 0; k < EDD; k++) EA[k] = _eap[k];                         \
        XLV = *(const float4*)(xl + (long)_s * HC + gc);                       \
    }

#define COMPUTE(EA, XLV)                                                       \
    {                                                                          \
        float ez0 = 0.f, ez1 = 0.f, ez2 = 0.f, ez3 = 0.f;                      \
        _Pragma("unroll")                                                      \
        for (int k = 0; k < EDD; k++) {                                        \
            ez0 = fmaf(EA[k], wreg[k][0], ez0);                                \
            ez1 = fmaf(EA[k], wreg[k][1], ez1);                                \
            ez2 = fmaf(EA[k], wreg[k][2], ez2);                                \
            ez3 = fmaf(EA[k], wreg[k][3], ez3);                                \
        }                                                                      \
        float s0 = XLV.x + xrv.x + ez0;                                        \
        float s1 = XLV.y + xrv.y + ez1;                                        \
        float s2 = XLV.z + xrv.z + ez2;                                        \
        float s3 = XLV.w + xrv.w + ez3;                                        \
        s0 = (s0 > 0.f) ? s0 : 0.2f * s0;                                      \
        s1 = (s1 > 0.f) ? s1 : 0.2f * s1;                                      \
        s2 = (s2 > 0.f) ? s2 : 0.2f * s2;                                      \
        s3 = (s3 > 0.f) ? s3 : 0.2f * s3;                                      \
        float part = fmaf(s0, a4.x, fmaf(s1, a4.y,                             \
                     fmaf(s2, a4.z, s3 * a4.w)));                              \
        part += __shfl_xor(part, 1, 64);                                       \
        part += __shfl_xor(part, 2, 64);                                       \
        part += __shfl_xor(part, 4, 64);                                       \
        part += __shfl_xor(part, 8, 64);                                       \
        const float mn = fmaxf(m, part);                                       \
        const float cc = fast_exp(m - mn);                                     \
        const float ww = fast_exp(part - mn);                                  \
        l   = l * cc + ww;                                                     \
        ac0 = ac0 * cc + ww * XLV.x;                                           \
        ac1 = ac1 * cc + ww * XLV.y;                                           \
        ac2 = ac2 * cc + ww * XLV.z;                                           \
        ac3 = ac3 * cc + ww * XLV.w;                                           \
        m = mn;                                                                \
    }

    int p = p0;
    if (p < p1) PRELOAD(eaA, xlvA, p);
    while (p < p1) {
        if (p + 1 < p1) PRELOAD(eaB, xlvB, p + 1);
        COMPUTE(eaA, xlvA);
        p++;
        if (p >= p1) break;
        if (p + 1 < p1) PRELOAD(eaA, xlvA, p + 1);
        COMPUTE(eaB, xlvB);
        p++;
    }
#undef PRELOAD
#undef COMPUTE

    // ---- epilogue ----
    const float inv = 1.0f / (l + 1e-16f);
    float v0 = ac0 * inv, v1 = ac1 * inv, v2 = ac2 * inv, v3 = ac3 * inv;

    // head mean: sum across the 4 groups (xor 16, 32), then /4 + bias
    v0 += __shfl_xor(v0, 16, 64); v0 += __shfl_xor(v0, 32, 64);
    v1 += __shfl_xor(v1, 16, 64); v1 += __shfl_xor(v1, 32, 64);
    v2 += __shfl_xor(v2, 16, 64); v2 += __shfl_xor(v2, 32, 64);
    v3 += __shfl_xor(v3, 16, 64); v3 += __shfl_xor(v3, 32, 64);

    const float4 b4 = *(const float4*)(bias + cb);
    v0 = v0 * 0.25f + b4.x;
    v1 = v1 * 0.25f + b4.y;
    v2 = v2 * 0.25f + b4.z;
    v3 = v3 * 0.25f + b4.w;

    // LayerNorm over 64 channels (16 lanes x 4, replicated across groups)
    float s = (v0 + v1) + (v2 + v3);
    s += __shfl_xor(s, 1, 64); s += __shfl_xor(s, 2, 64);
    s += __shfl_xor(s, 4, 64); s += __shfl_xor(s, 8, 64);
    const float mu = s * (1.0f / 64.0f);
    const float d0 = v0 - mu, d1 = v1 - mu, d2 = v2 - mu, d3 = v3 - mu;
    float q = (d0 * d0 + d1 * d1) + (d2 * d2 + d3 * d3);
    q += __shfl_xor(q, 1, 64); q += __shfl_xor(q, 2, 64);
    q += __shfl_xor(q, 4, 64); q += __shfl_xor(q, 8, 64);
    const float rs = rsqrtf(q * (1.0f / 64.0f) + 1e-5f);

    const float4 g4 = *(const float4*)(lng + cb);
    const float4 c4 = *(const float4*)(lnb + cb);
    float y0 = d0 * rs * g4.x + c4.x;
    float y1 = d1 * rs * g4.y + c4.y;
    float y2 = d2 * rs * g4.z + c4.z;
    float y3 = d3 * rs * g4.w + c4.w;

    if (lane < 16) {   // group 0 stores (all groups replicate)
        if (mode == 0) {
            float4 o;
            o.x = gelu_exact(y0); o.y = gelu_exact(y1);
            o.z = gelu_exact(y2); o.w = gelu_exact(y3);
            *(float4*)(x1out + (long)n * DD + cb) = o;
        } else {
            const float4 id = *(const float4*)(identity + (long)n * DD + cb);
            float4 o;
            o.x = gelu_exact(y0 + id.x); o.y = gelu_exact(y1 + id.y);
            o.z = gelu_exact(y2 + id.z); o.w = gelu_exact(y3 + id.w);
            *(float4*)(outp + (long)n * DD + cb) = o;
        }
    }
}

// ---------- launch ----------
extern "C" void kernel_launch(void* const* d_in, const int* in_sizes, int n_in,
                              void* d_out, int out_size, void* d_ws, size_t ws_size,
                              hipStream_t stream) {
    (void)in_sizes; (void)n_in; (void)out_size; (void)ws_size;

    const float* h     = (const float*)d_in[0];
    const int*   ei    = (const int*)d_in[1];
    const float* ea    = (const float*)d_in[2];
    const float* g1Wl  = (const float*)d_in[3];
    const float* g1bl  = (const float*)d_in[4];
    const float* g1Wr  = (const float*)d_in[5];
    const float* g1br  = (const float*)d_in[6];
    const float* g1We  = (const float*)d_in[7];
    const float* g1att = (const float*)d_in[8];
    const float* g1bias= (const float*)d_in[9];
    const float* ln1g  = (const float*)d_in[10];
    const float* ln1b  = (const float*)d_in[11];
    const float* g2Wl  = (const float*)d_in[12];
    const float* g2bl  = (const float*)d_in[13];
    const float* g2Wr  = (const float*)d_in[14];
    const float* g2br  = (const float*)d_in[15];
    const float* g2We  = (const float*)d_in[16];
    const float* g2att = (const float*)d_in[17];
    const float* g2bias= (const float*)d_in[18];
    const float* ln2g  = (const float*)d_in[19];
    const float* ln2b  = (const float*)d_in[20];

    float* out = (float*)d_out;

    // workspace layout (4-byte units), ~143 MB
    float* ws = (float*)d_ws;
    size_t o = 0;
    float* xl     = ws + o;         o += 12800000;   // N*256
    float* xr     = ws + o;         o += 12800000;   // N*256
    float* x1     = ws + o;         o += 3200000;    // N*64
    int*   rowptr = (int*)(ws + o); o += 50004;      // N+1
    int*   deg    = (int*)(ws + o); o += 50000;
    int*   cursor = (int*)(ws + o); o += 50000;
    int*   bsum   = (int*)(ws + o); o += 256;
    int*   srcs   = (int*)(ws + o); o += 400000;
    float* ea_s   = ws + o;         o += 6400000;    // E*16, CSR-sorted edge attrs

    const int GEMM_BLOCKS  = (NN + 31) / 32;    // 1563
    const int SCAN_BLOCKS  = (NN + 255) / 256;  // 196
    const int EDGE_BLOCKS  = (EE + 255) / 256;  // 1563
    const int GAT_BLOCKS   = (NN + 3) / 4;      // 12500 -> 50000 waves

    // ----- CSR build (once; graph identical for both layers) -----
    fill_u32<<<256, 256, 0, stream>>>((unsigned*)deg, 0u, NN);
    hist_k<<<EDGE_BLOCKS, 256, 0, stream>>>(ei, deg);
    scan1_k<<<SCAN_BLOCKS, 256, 0, stream>>>(deg, rowptr, bsum);
    scan2_k<<<1, 256, 0, stream>>>(bsum, SCAN_BLOCKS);
    scan3_k<<<SCAN_BLOCKS, 256, 0, stream>>>(rowptr, bsum, cursor);
    scatter_k<<<EDGE_BLOCKS, 256, 0, stream>>>(ei, cursor, ea, srcs, ea_s);

    // ----- layer 1 -----
    gemm_node<<<GEMM_BLOCKS, 256, 0, stream>>>(h, g1Wl, g1bl, xl);
    gemm_node<<<GEMM_BLOCKS, 256, 0, stream>>>(h, g1Wr, g1br, xr);
    gat_fused_k<<<GAT_BLOCKS, 256, 0, stream>>>(rowptr, srcs, ea_s, g1We, g1att,
                                                xl, xr, g1bias, ln1g, ln1b, h, x1, out, 0);

    // ----- layer 2 -----
    gemm_node<<<GEMM_BLOCKS, 256, 0, stream>>>(x1, g2Wl, g2bl, xl);
    gemm_node<<<GEMM_BLOCKS, 256, 0, stream>>>(x1, g2Wr, g2br, xr);
    gat_fused_k<<<GAT_BLOCKS, 256, 0, stream>>>(rowptr, srcs, ea_s, g2We, g2att,
                                                xl, xr, g2bias, ln2g, ln2b, h, x1, out, 1);
}